// Round 6
// baseline (300.024 us; speedup 1.0000x reference)
//
#include <hip/hip_runtime.h>
#include <math.h>

#define Mq 12288          // B*T
#define Nq 768            // C (per-matrix output width)
#define Kq 768            // C (reduce dim)
#define Tq 768
#define Bq 16
#define Cq 768
#define BK 64             // K-tile (bf16) = 128 B = 8 x 16B chunks
#define BM 128            // token tile
#define BN 128            // channel tile

typedef __bf16 bf16x8 __attribute__((ext_vector_type(8)));
typedef __bf16 bf16x4 __attribute__((ext_vector_type(4)));
typedef __bf16 bf16x2 __attribute__((ext_vector_type(2)));
typedef float  floatx4  __attribute__((ext_vector_type(4)));
typedef float  floatx16 __attribute__((ext_vector_type(16)));

// async 16B/lane global->LDS (LDS operand is wave-uniform base; HW adds lane*16)
#define GLD_LDS16(g, l) __builtin_amdgcn_global_load_lds(                      \
    (const __attribute__((address_space(1))) unsigned int*)(g),                \
    (__attribute__((address_space(3))) unsigned int*)(l), 16, 0, 0)

// ---------------------------------------------------------------------------
// Fused prep: blocks [0,9216) token-shift mix -> bf16 xk/xv/xr;
//             blocks [9216,11520) weight f32 -> bf16 pool (k|v|r|o rows).
// ---------------------------------------------------------------------------
__global__ __launch_bounds__(256)
void prep_kernel(const float* __restrict__ x,
                 const float* __restrict__ mk, const float* __restrict__ mv,
                 const float* __restrict__ mr,
                 const float* __restrict__ Wk, const float* __restrict__ Wv,
                 const float* __restrict__ Wr, const float* __restrict__ Wo,
                 __bf16* __restrict__ xk, __bf16* __restrict__ xv,
                 __bf16* __restrict__ xr, __bf16* __restrict__ wp)
{
    const int bid = blockIdx.x;
    if (bid < 9216) {
        const int i  = bid * 256 + threadIdx.x;       // one float4 of channels
        const int c4 = i % (Cq / 4);
        const int m  = i / (Cq / 4);
        const int t  = m % Tq;
        const int c0 = c4 * 4;

        const float4 xc = *(const float4*)(x + (size_t)m * Cq + c0);
        float4 xp = make_float4(0.f, 0.f, 0.f, 0.f);
        if (t > 0) xp = *(const float4*)(x + (size_t)(m - 1) * Cq + c0);

        const float4 k4 = *(const float4*)(mk + c0);
        const float4 v4 = *(const float4*)(mv + c0);
        const float4 r4 = *(const float4*)(mr + c0);

        bf16x4 ok = { (__bf16)fmaf(k4.x, xc.x - xp.x, xp.x),
                      (__bf16)fmaf(k4.y, xc.y - xp.y, xp.y),
                      (__bf16)fmaf(k4.z, xc.z - xp.z, xp.z),
                      (__bf16)fmaf(k4.w, xc.w - xp.w, xp.w) };
        bf16x4 ov = { (__bf16)fmaf(v4.x, xc.x - xp.x, xp.x),
                      (__bf16)fmaf(v4.y, xc.y - xp.y, xp.y),
                      (__bf16)fmaf(v4.z, xc.z - xp.z, xp.z),
                      (__bf16)fmaf(v4.w, xc.w - xp.w, xp.w) };
        bf16x4 orr = { (__bf16)fmaf(r4.x, xc.x - xp.x, xp.x),
                       (__bf16)fmaf(r4.y, xc.y - xp.y, xp.y),
                       (__bf16)fmaf(r4.z, xc.z - xp.z, xp.z),
                       (__bf16)fmaf(r4.w, xc.w - xp.w, xp.w) };
        const size_t o = (size_t)m * Cq + c0;
        *(bf16x4*)(xk + o) = ok;
        *(bf16x4*)(xv + o) = ov;
        *(bf16x4*)(xr + o) = orr;
    } else {
        const int i   = (bid - 9216) * 256 + threadIdx.x; // one float4
        const int a   = i / 147456;                       // which matrix
        const int off = (i - a * 147456) * 4;
        const float* s = (a == 0) ? Wk : (a == 1) ? Wv : (a == 2) ? Wr : Wo;
        const float4 v = *(const float4*)(s + off);
        bf16x4 r = { (__bf16)v.x, (__bf16)v.y, (__bf16)v.z, (__bf16)v.w };
        *(bf16x4*)(wp + (size_t)a * 589824 + off) = r;
    }
}

// ---------------------------------------------------------------------------
// bf16 MFMA GEMM v3: 128x128 tile, BK=64, 32x32x16 MFMA, 256 thr (4 waves),
// wave tile 64 tok x 64 ch (2x2 MFMA tiles, acc 2x2x16 f32).
// W operand: DIRECT global->VGPR loads (A-operand layout row=lane&31,
//            k-octet=lane>>5) — L2-resident per XCD, skips LDS entirely.
// X operand: LDS-staged (16 KB) via global_load_lds + XOR-8 swizzle.
// K-loop: read X frags -> barrier -> stage next tile DURING MFMA -> barrier.
// Grid 1-D, XCD-swizzled: xcd=blk&7 owns m-tiles [xcd*12, xcd*12+12).
// ---------------------------------------------------------------------------
template<bool KVR>
__global__ __launch_bounds__(256, 3)
void mfma_gemm(const __bf16* __restrict__ A0, const __bf16* __restrict__ A1,
               const __bf16* __restrict__ A2,
               const __bf16* __restrict__ W,
               __bf16* __restrict__ OUTb, float* __restrict__ OUTf)
{
    __shared__ __bf16 As[BM * BK];    // 16 KB (tokens x K)

    const int STRIPS = KVR ? 18 : 6;

    // ---- XCD-aware swizzle (8 XCDs, 96 m-tiles = 8 x 12)
    const int i_    = blockIdx.x;
    const int xcd   = i_ & 7;
    const int j_    = i_ >> 3;
    const int strip = j_ % STRIPS;
    const int mt    = xcd * 12 + j_ / STRIPS;

    const int tid   = threadIdx.x;
    const int wave  = tid >> 6;
    const int lane  = tid & 63;
    const int m0    = mt * BM;
    const int matid = KVR ? strip / 6 : 0;
    const int n0    = KVR ? (strip % 6) * BN : strip * BN;
    const int wn0   = strip * BN;

    const __bf16* A = KVR ? (matid == 0 ? A0 : matid == 1 ? A1 : A2) : A0;

    // ---- staging: 4 glds instrs per wave, each = 8 rows x 128 B
    const int r8 = lane >> 3;             // row within 8-row group
    const int sc = (lane & 7) ^ r8;       // XOR-8 swizzled source chunk
    const __bf16* gA[4];  __bf16* lA[4];
#pragma unroll
    for (int i = 0; i < 4; ++i) {
        const int row = (wave * 4 + i) * 8 + r8;
        gA[i] = A + (size_t)(m0 + row) * Kq + sc * 8;
        lA[i] = As + (wave * 4 + i) * 512;
    }

    // ---- compute coords
    const int qn = wave & 1;              // channel half (64)
    const int qm = wave >> 1;             // token half (64)
    const int l31 = lane & 31;
    const int oct = lane >> 5;            // k-octet select

    // X (B-operand) LDS rows; W (A-operand) global row pointers
    const int xRowB = qm * 64 + l31;                       // + tt*32
    const __bf16* wPtr[2];
#pragma unroll
    for (int ct = 0; ct < 2; ++ct)
        wPtr[ct] = W + (size_t)(wn0 + qn * 64 + ct * 32 + l31) * Kq + oct * 8;

    floatx16 acc[2][2] = {};              // [ct][tt]

    // prologue: stage tile 0
#pragma unroll
    for (int i = 0; i < 4; ++i) { GLD_LDS16(gA[i], lA[i]); gA[i] += BK; }
    __syncthreads();

    for (int kt = 0; kt < Kq / BK; ++kt) {
        // ---- read X fragments for this tile (8 x ds_read_b128)
        bf16x8 xF[2][4];                  // [tt][ks]
#pragma unroll
        for (int tt = 0; tt < 2; ++tt) {
            const int r = xRowB + tt * 32;
#pragma unroll
            for (int ks = 0; ks < 4; ++ks) {
                const int phys = ((ks << 1) | oct) ^ (r & 7);
                xF[tt][ks] = *(const bf16x8*)(As + r * BK + phys * 8);
            }
        }
        __syncthreads();                  // frags in VGPR; LDS reusable

        if (kt + 1 < Kq / BK) {           // stage next tile during MFMA
#pragma unroll
            for (int i = 0; i < 4; ++i) { GLD_LDS16(gA[i], lA[i]); gA[i] += BK; }
        }

        // ---- W fragments direct from global (L2) + MFMA
        bf16x8 wF[2][4];                  // [ct][ks]
#pragma unroll
        for (int ct = 0; ct < 2; ++ct)
#pragma unroll
            for (int ks = 0; ks < 4; ++ks)
                wF[ct][ks] = *(const bf16x8*)(wPtr[ct] + kt * BK + ks * 16);

#pragma unroll
        for (int ks = 0; ks < 4; ++ks)
#pragma unroll
            for (int ct = 0; ct < 2; ++ct)
#pragma unroll
                for (int tt = 0; tt < 2; ++tt)
                    acc[ct][tt] = __builtin_amdgcn_mfma_f32_32x32x16_bf16(
                        wF[ct][ks], xF[tt][ks], acc[ct][tt], 0, 0, 0);

        __syncthreads();                  // staged tile fully in LDS
    }

    // ---- epilogue: C/D 32x32 map: col=lane&31, row=(reg&3)+8*(reg>>2)+4*oct
#pragma unroll
    for (int ct = 0; ct < 2; ++ct) {
        const int ch0 = n0 + qn * 64 + ct * 32 + oct * 4;
#pragma unroll
        for (int tt = 0; tt < 2; ++tt) {
            const int tok = m0 + qm * 64 + tt * 32 + l31;
#pragma unroll
            for (int g = 0; g < 4; ++g) {
                const int ch = ch0 + g * 8;
                float v0 = acc[ct][tt][g * 4 + 0];
                float v1 = acc[ct][tt][g * 4 + 1];
                float v2 = acc[ct][tt][g * 4 + 2];
                float v3 = acc[ct][tt][g * 4 + 3];
                if (KVR) {
                    if (matid == 0) {
                        v0 = expf(fminf(v0, 60.f)); v1 = expf(fminf(v1, 60.f));
                        v2 = expf(fminf(v2, 60.f)); v3 = expf(fminf(v3, 60.f));
                    } else if (matid == 2) {
                        v0 = 1.f / (1.f + expf(-v0)); v1 = 1.f / (1.f + expf(-v1));
                        v2 = 1.f / (1.f + expf(-v2)); v3 = 1.f / (1.f + expf(-v3));
                    }
                    bf16x4 o = { (__bf16)v0, (__bf16)v1, (__bf16)v2, (__bf16)v3 };
                    *(bf16x4*)(OUTb + (size_t)matid * Mq * Nq +
                               (size_t)tok * Nq + ch) = o;
                } else {
                    floatx4 o = { v0, v1, v2, v3 };
                    *(floatx4*)(OUTf + (size_t)tok * Nq + ch) = o;
                }
            }
        }
    }
}

// ---------------------------------------------------------------------------
// Segmented RWKV scan: block = 64 lanes x 2 channels x 16 segments of 48.
// ---------------------------------------------------------------------------
#define SEG 16
#define SLEN (Tq / SEG)   // 48

__global__ __launch_bounds__(1024)
void scan_kernel(const __bf16* __restrict__ kb, const __bf16* __restrict__ vb,
                 __bf16* rb,
                 const float* __restrict__ td, const float* __restrict__ tf)
{
    __shared__ float2 aS[SEG][64];
    __shared__ float2 bS[SEG][64];

    const int cx  = threadIdx.x;          // 0..63 -> channel pair
    const int seg = threadIdx.y;          // 0..15
    const int c0  = blockIdx.x * 128 + cx * 2;
    const int b   = blockIdx.y;

    const float d0 = expf(td[c0]),     d1 = expf(td[c0 + 1]);
    const float w0 = expf(-d0),        w1 = expf(-d1);      // per-step decay
    const float u0 = expf(tf[c0]),     u1 = expf(tf[c0 + 1]);

    const size_t base = ((size_t)b * Tq + seg * SLEN) * Cq + c0;

    // phase 1: local segment sums (zero init)
    float a0 = 0.f, a1 = 0.f, s0 = 0.f, s1 = 0.f;
#pragma unroll 4
    for (int t = 0; t < SLEN; ++t) {
        const size_t idx = base + (size_t)t * Cq;
        const bf16x2 k2 = *(const bf16x2*)(kb + idx);
        const bf16x2 v2 = *(const bf16x2*)(vb + idx);
        const float k0 = (float)k2[0], k1 = (float)k2[1];
        a0 = fmaf(w0, a0, k0 * (float)v2[0]);
        a1 = fmaf(w1, a1, k1 * (float)v2[1]);
        s0 = fmaf(w0, s0, k0);
        s1 = fmaf(w1, s1, k1);
    }
    aS[seg][cx] = make_float2(a0, a1);
    bS[seg][cx] = make_float2(s0, s1);
    __syncthreads();

    // phase 2: serial prefix over segments (first row of threads)
    if (seg == 0) {
        const float W0 = expf(-d0 * (float)SLEN);   // w0^SLEN
        const float W1 = expf(-d1 * (float)SLEN);
        float ia0 = 0.f, ia1 = 0.f, ib0 = 0.f, ib1 = 0.f;
#pragma unroll
        for (int s = 0; s < SEG; ++s) {
            const float2 ta = aS[s][cx];
            const float2 tb = bS[s][cx];
            aS[s][cx] = make_float2(ia0, ia1);
            bS[s][cx] = make_float2(ib0, ib1);
            ia0 = fmaf(W0, ia0, ta.x);  ia1 = fmaf(W1, ia1, ta.y);
            ib0 = fmaf(W0, ib0, tb.x);  ib1 = fmaf(W1, ib1, tb.y);
        }
    }
    __syncthreads();

    // phase 3: outputs with incoming state
    const float2 ain = aS[seg][cx];
    const float2 bin = bS[seg][cx];
    a0 = ain.x; a1 = ain.y; s0 = bin.x; s1 = bin.y;
#pragma unroll 2
    for (int t = 0; t < SLEN; ++t) {
        const size_t idx = base + (size_t)t * Cq;
        const bf16x2 k2 = *(const bf16x2*)(kb + idx);
        const bf16x2 v2 = *(const bf16x2*)(vb + idx);
        const bf16x2 r2 = *(const bf16x2*)(rb + idx);   // sigmoid(r)
        const float k0 = (float)k2[0], k1 = (float)k2[1];
        const float kv0 = k0 * (float)v2[0], kv1 = k1 * (float)v2[1];
        const float n0 = fmaf(u0, kv0, a0), n1 = fmaf(u1, kv1, a1);
        const float e0 = fmaf(u0, k0, s0) + 1e-8f;
        const float e1 = fmaf(u1, k1, s1) + 1e-8f;
        bf16x2 o = { (__bf16)((float)r2[0] * n0 / e0),
                     (__bf16)((float)r2[1] * n1 / e1) };
        *(bf16x2*)(rb + idx) = o;
        a0 = fmaf(w0, a0, kv0);  a1 = fmaf(w1, a1, kv1);
        s0 = fmaf(w0, s0, k0);   s1 = fmaf(w1, s1, k1);
    }
}

extern "C" void kernel_launch(void* const* d_in, const int* in_sizes, int n_in,
                              void* d_out, int out_size, void* d_ws, size_t ws_size,
                              hipStream_t stream)
{
    const float* x  = (const float*)d_in[0];
    const float* td = (const float*)d_in[1];
    const float* tf = (const float*)d_in[2];
    const float* mk = (const float*)d_in[3];
    const float* mv = (const float*)d_in[4];
    const float* mr = (const float*)d_in[5];
    const float* Wk = (const float*)d_in[6];
    const float* Wv = (const float*)d_in[7];
    const float* Wr = (const float*)d_in[8];
    const float* Wo = (const float*)d_in[9];

    const size_t MC = (size_t)Mq * Cq;      // 9,437,184 elems

    // d_out doubles as scratch for xk/xv (2 x bf16 MC = out bytes exactly)
    __bf16* xk = (__bf16*)d_out;
    __bf16* xv = xk + MC;

    // ws: xr | kbuf | vbuf | rbuf(->rwkv) | weights(bf16 x4)  = ~80 MB
    __bf16* xr   = (__bf16*)d_ws;
    __bf16* kbuf = xr + MC;                 // kbuf,vbuf,rbuf contiguous
    __bf16* vbuf = kbuf + MC;
    __bf16* rbuf = vbuf + MC;
    __bf16* Wp   = rbuf + MC;
    __bf16* Wob  = Wp + 3 * 589824;

    prep_kernel<<<11520, 256, 0, stream>>>(x, mk, mv, mr, Wk, Wv, Wr, Wo,
                                           xk, xv, xr, Wp);

    // fused k|v|r GEMM: 18 strips x 96 m-tiles, XCD-swizzled 1-D grid
    mfma_gemm<true><<<18 * 96, 256, 0, stream>>>(
        xk, xv, xr, Wp, kbuf, nullptr);

    scan_kernel<<<dim3(Cq / 128, Bq), dim3(64, SEG), 0, stream>>>(
        kbuf, vbuf, rbuf, td, tf);

    mfma_gemm<false><<<6 * 96, 256, 0, stream>>>(
        rbuf, nullptr, nullptr, Wob, nullptr, (float*)d_out);
}

// Round 7
// 272.485 us; speedup vs baseline: 1.1011x; 1.1011x over previous
//
#include <hip/hip_runtime.h>
#include <math.h>

#define Mq 12288          // B*T
#define Nq 768            // C (per-matrix output width)
#define Kq 768            // C (reduce dim)
#define Tq 768
#define Bq 16
#define Cq 768
#define BK 64             // K-tile (bf16) = 128 B = 8 x 16B chunks
#define BM 128            // token tile
#define BN 128            // channel tile

typedef __bf16 bf16x8 __attribute__((ext_vector_type(8)));
typedef __bf16 bf16x4 __attribute__((ext_vector_type(4)));
typedef __bf16 bf16x2 __attribute__((ext_vector_type(2)));
typedef float  floatx4 __attribute__((ext_vector_type(4)));

// async 16B/lane global->LDS (LDS operand is wave-uniform base; HW adds lane*16)
#define GLD_LDS16(g, l) __builtin_amdgcn_global_load_lds(                      \
    (const __attribute__((address_space(1))) unsigned int*)(g),                \
    (__attribute__((address_space(3))) unsigned int*)(l), 16, 0, 0)

// ---------------------------------------------------------------------------
// Fused prep: blocks [0,9216) token-shift mix -> bf16 xk/xv/xr;
//             blocks [9216,11520) weight f32 -> bf16 pool (k|v|r|o rows).
// ---------------------------------------------------------------------------
__global__ __launch_bounds__(256)
void prep_kernel(const float* __restrict__ x,
                 const float* __restrict__ mk, const float* __restrict__ mv,
                 const float* __restrict__ mr,
                 const float* __restrict__ Wk, const float* __restrict__ Wv,
                 const float* __restrict__ Wr, const float* __restrict__ Wo,
                 __bf16* __restrict__ xk, __bf16* __restrict__ xv,
                 __bf16* __restrict__ xr, __bf16* __restrict__ wp)
{
    const int bid = blockIdx.x;
    if (bid < 9216) {
        const int i  = bid * 256 + threadIdx.x;       // one float4 of channels
        const int c4 = i % (Cq / 4);
        const int m  = i / (Cq / 4);
        const int t  = m % Tq;
        const int c0 = c4 * 4;

        const float4 xc = *(const float4*)(x + (size_t)m * Cq + c0);
        float4 xp = make_float4(0.f, 0.f, 0.f, 0.f);
        if (t > 0) xp = *(const float4*)(x + (size_t)(m - 1) * Cq + c0);

        const float4 k4 = *(const float4*)(mk + c0);
        const float4 v4 = *(const float4*)(mv + c0);
        const float4 r4 = *(const float4*)(mr + c0);

        bf16x4 ok = { (__bf16)fmaf(k4.x, xc.x - xp.x, xp.x),
                      (__bf16)fmaf(k4.y, xc.y - xp.y, xp.y),
                      (__bf16)fmaf(k4.z, xc.z - xp.z, xp.z),
                      (__bf16)fmaf(k4.w, xc.w - xp.w, xp.w) };
        bf16x4 ov = { (__bf16)fmaf(v4.x, xc.x - xp.x, xp.x),
                      (__bf16)fmaf(v4.y, xc.y - xp.y, xp.y),
                      (__bf16)fmaf(v4.z, xc.z - xp.z, xp.z),
                      (__bf16)fmaf(v4.w, xc.w - xp.w, xp.w) };
        bf16x4 orr = { (__bf16)fmaf(r4.x, xc.x - xp.x, xp.x),
                       (__bf16)fmaf(r4.y, xc.y - xp.y, xp.y),
                       (__bf16)fmaf(r4.z, xc.z - xp.z, xp.z),
                       (__bf16)fmaf(r4.w, xc.w - xp.w, xp.w) };
        const size_t o = (size_t)m * Cq + c0;
        *(bf16x4*)(xk + o) = ok;
        *(bf16x4*)(xv + o) = ov;
        *(bf16x4*)(xr + o) = orr;
    } else {
        const int i   = (bid - 9216) * 256 + threadIdx.x; // one float4
        const int a   = i / 147456;                       // which matrix
        const int off = (i - a * 147456) * 4;
        const float* s = (a == 0) ? Wk : (a == 1) ? Wv : (a == 2) ? Wr : Wo;
        const float4 v = *(const float4*)(s + off);
        bf16x4 r = { (__bf16)v.x, (__bf16)v.y, (__bf16)v.z, (__bf16)v.w };
        *(bf16x4*)(wp + (size_t)a * 589824 + off) = r;
    }
}

// ---------------------------------------------------------------------------
// bf16 MFMA GEMM (m97 config): 128x128 tile, BK=64, 256 thr (4 waves),
// 16x16x32 MFMA, 4x4 frag tile per wave (wave = 64 ch x 64 tok quadrant).
// reads/MFMA = 0.5 (16 ds_read_b128 per 32 MFMA per wave-kt).
// W is the MFMA A operand -> D's register dim = 4 consecutive channels ->
// vectorized bf16x4/float4 stores. XOR-8 source-side chunk swizzle (proven
// zero-conflict in R4/R5). 1-D grid, XCD-aware swizzle: xcd=blk&7 owns
// m-tiles [xcd*12, xcd*12+12); strip-fastest within.
// ---------------------------------------------------------------------------
template<bool KVR>
__global__ __launch_bounds__(256, 4)
void mfma_gemm(const __bf16* __restrict__ A0, const __bf16* __restrict__ A1,
               const __bf16* __restrict__ A2,
               const __bf16* __restrict__ W,
               __bf16* __restrict__ OUTb, float* __restrict__ OUTf)
{
    __shared__ __bf16 As[BM * BK];    // 16 KB (tokens  x K)
    __shared__ __bf16 Bs[BN * BK];    // 16 KB (channels x K)

    const int STRIPS = KVR ? 18 : 6;

    // ---- XCD-aware swizzle (8 XCDs, 96 m-tiles = 8 x 12)
    const int i_    = blockIdx.x;
    const int xcd   = i_ & 7;
    const int j_    = i_ >> 3;
    const int strip = j_ % STRIPS;
    const int mt    = xcd * 12 + j_ / STRIPS;

    const int tid   = threadIdx.x;
    const int wave  = tid >> 6;
    const int lane  = tid & 63;
    const int m0    = mt * BM;
    const int matid = KVR ? strip / 6 : 0;
    const int n0    = KVR ? (strip % 6) * BN : strip * BN;
    const int wn0   = strip * BN;

    const __bf16* A = KVR ? (matid == 0 ? A0 : matid == 1 ? A1 : A2) : A0;

    // ---- staging: per operand 16 KB/kt = 16 glds instrs (4 per wave)
    const int r8 = lane >> 3;             // row within 8-row group
    const int sc = (lane & 7) ^ r8;       // XOR-8 swizzled source chunk
    const __bf16* gA[4];  __bf16* lA[4];
    const __bf16* gB[4];  __bf16* lB[4];
#pragma unroll
    for (int i = 0; i < 4; ++i) {
        const int row = (wave * 4 + i) * 8 + r8;
        gA[i] = A + (size_t)(m0  + row) * Kq + sc * 8;
        gB[i] = W + (size_t)(wn0 + row) * Kq + sc * 8;
        lA[i] = As + (wave * 4 + i) * 512;     // 1 KB per instr
        lB[i] = Bs + (wave * 4 + i) * 512;
    }

    // ---- reader coords: wave quadrant qn (ch half) x qm (tok half)
    const int qn = wave & 1;
    const int qm = wave >> 1;
    const int wRow = qn * 64 + (lane & 15);   // + i*16, in Bs (channels)
    const int xRow = qm * 64 + (lane & 15);   // + j*16, in As (tokens)
    const int lk   = lane >> 4;               // logical 16B chunk within K=32

    floatx4 acc[4][4];                    // [i=ch][j=tok]
#pragma unroll
    for (int i = 0; i < 4; ++i)
#pragma unroll
        for (int j = 0; j < 4; ++j) acc[i][j] = (floatx4){0.f, 0.f, 0.f, 0.f};

    for (int kt = 0; kt < Kq / BK; ++kt) {
#pragma unroll
        for (int i = 0; i < 4; ++i) {
            GLD_LDS16(gA[i], lA[i]); gA[i] += BK;
            GLD_LDS16(gB[i], lB[i]); gB[i] += BK;
        }
        __syncthreads();                  // drains vmcnt(0): tile in LDS

#pragma unroll
        for (int kk = 0; kk < 2; ++kk) {
            bf16x8 wF[4], xF[4];
#pragma unroll
            for (int i = 0; i < 4; ++i) {
                const int r = wRow + i * 16;
                wF[i] = *(const bf16x8*)(Bs + r * BK +
                                         (((kk << 2) | lk) ^ (r & 7)) * 8);
            }
#pragma unroll
            for (int j = 0; j < 4; ++j) {
                const int r = xRow + j * 16;
                xF[j] = *(const bf16x8*)(As + r * BK +
                                         (((kk << 2) | lk) ^ (r & 7)) * 8);
            }
#pragma unroll
            for (int i = 0; i < 4; ++i)
#pragma unroll
                for (int j = 0; j < 4; ++j)
                    acc[i][j] = __builtin_amdgcn_mfma_f32_16x16x32_bf16(
                        wF[i], xF[j], acc[i][j], 0, 0, 0);
        }
        __syncthreads();                  // LDS reads done before overwrite
    }

    // ---- epilogue: D col = token (lane&15), row-reg = 4 consecutive channels
#pragma unroll
    for (int j = 0; j < 4; ++j) {
        const int tok = m0 + qm * 64 + j * 16 + (lane & 15);
#pragma unroll
        for (int i = 0; i < 4; ++i) {
            const int ch = n0 + qn * 64 + i * 16 + (lane >> 4) * 4;
            if (KVR) {
                float v0 = acc[i][j][0], v1 = acc[i][j][1];
                float v2 = acc[i][j][2], v3 = acc[i][j][3];
                if (matid == 0) {
                    v0 = expf(fminf(v0, 60.f)); v1 = expf(fminf(v1, 60.f));
                    v2 = expf(fminf(v2, 60.f)); v3 = expf(fminf(v3, 60.f));
                } else if (matid == 2) {
                    v0 = 1.f / (1.f + expf(-v0)); v1 = 1.f / (1.f + expf(-v1));
                    v2 = 1.f / (1.f + expf(-v2)); v3 = 1.f / (1.f + expf(-v3));
                }
                bf16x4 o = { (__bf16)v0, (__bf16)v1, (__bf16)v2, (__bf16)v3 };
                *(bf16x4*)(OUTb + (size_t)matid * Mq * Nq +
                           (size_t)tok * Nq + ch) = o;
            } else {
                floatx4 o = acc[i][j];
                *(floatx4*)(OUTf + (size_t)tok * Nq + ch) = o;
            }
        }
    }
}

// ---------------------------------------------------------------------------
// Segmented RWKV scan: block = 64 lanes x 2 channels x 16 segments of 48.
// ---------------------------------------------------------------------------
#define SEG 16
#define SLEN (Tq / SEG)   // 48

__global__ __launch_bounds__(1024)
void scan_kernel(const __bf16* __restrict__ kb, const __bf16* __restrict__ vb,
                 __bf16* rb,
                 const float* __restrict__ td, const float* __restrict__ tf)
{
    __shared__ float2 aS[SEG][64];
    __shared__ float2 bS[SEG][64];

    const int cx  = threadIdx.x;          // 0..63 -> channel pair
    const int seg = threadIdx.y;          // 0..15
    const int c0  = blockIdx.x * 128 + cx * 2;
    const int b   = blockIdx.y;

    const float d0 = expf(td[c0]),     d1 = expf(td[c0 + 1]);
    const float w0 = expf(-d0),        w1 = expf(-d1);      // per-step decay
    const float u0 = expf(tf[c0]),     u1 = expf(tf[c0 + 1]);

    const size_t base = ((size_t)b * Tq + seg * SLEN) * Cq + c0;

    // phase 1: local segment sums (zero init)
    float a0 = 0.f, a1 = 0.f, s0 = 0.f, s1 = 0.f;
#pragma unroll 4
    for (int t = 0; t < SLEN; ++t) {
        const size_t idx = base + (size_t)t * Cq;
        const bf16x2 k2 = *(const bf16x2*)(kb + idx);
        const bf16x2 v2 = *(const bf16x2*)(vb + idx);
        const float k0 = (float)k2[0], k1 = (float)k2[1];
        a0 = fmaf(w0, a0, k0 * (float)v2[0]);
        a1 = fmaf(w1, a1, k1 * (float)v2[1]);
        s0 = fmaf(w0, s0, k0);
        s1 = fmaf(w1, s1, k1);
    }
    aS[seg][cx] = make_float2(a0, a1);
    bS[seg][cx] = make_float2(s0, s1);
    __syncthreads();

    // phase 2: serial prefix over segments (first row of threads)
    if (seg == 0) {
        const float W0 = expf(-d0 * (float)SLEN);   // w0^SLEN
        const float W1 = expf(-d1 * (float)SLEN);
        float ia0 = 0.f, ia1 = 0.f, ib0 = 0.f, ib1 = 0.f;
#pragma unroll
        for (int s = 0; s < SEG; ++s) {
            const float2 ta = aS[s][cx];
            const float2 tb = bS[s][cx];
            aS[s][cx] = make_float2(ia0, ia1);
            bS[s][cx] = make_float2(ib0, ib1);
            ia0 = fmaf(W0, ia0, ta.x);  ia1 = fmaf(W1, ia1, ta.y);
            ib0 = fmaf(W0, ib0, tb.x);  ib1 = fmaf(W1, ib1, tb.y);
        }
    }
    __syncthreads();

    // phase 3: outputs with incoming state
    const float2 ain = aS[seg][cx];
    const float2 bin = bS[seg][cx];
    a0 = ain.x; a1 = ain.y; s0 = bin.x; s1 = bin.y;
#pragma unroll 2
    for (int t = 0; t < SLEN; ++t) {
        const size_t idx = base + (size_t)t * Cq;
        const bf16x2 k2 = *(const bf16x2*)(kb + idx);
        const bf16x2 v2 = *(const bf16x2*)(vb + idx);
        const bf16x2 r2 = *(const bf16x2*)(rb + idx);   // sigmoid(r)
        const float k0 = (float)k2[0], k1 = (float)k2[1];
        const float kv0 = k0 * (float)v2[0], kv1 = k1 * (float)v2[1];
        const float n0 = fmaf(u0, kv0, a0), n1 = fmaf(u1, kv1, a1);
        const float e0 = fmaf(u0, k0, s0) + 1e-8f;
        const float e1 = fmaf(u1, k1, s1) + 1e-8f;
        bf16x2 o = { (__bf16)((float)r2[0] * n0 / e0),
                     (__bf16)((float)r2[1] * n1 / e1) };
        *(bf16x2*)(rb + idx) = o;
        a0 = fmaf(w0, a0, kv0);  a1 = fmaf(w1, a1, kv1);
        s0 = fmaf(w0, s0, k0);   s1 = fmaf(w1, s1, k1);
    }
}

extern "C" void kernel_launch(void* const* d_in, const int* in_sizes, int n_in,
                              void* d_out, int out_size, void* d_ws, size_t ws_size,
                              hipStream_t stream)
{
    const float* x  = (const float*)d_in[0];
    const float* td = (const float*)d_in[1];
    const float* tf = (const float*)d_in[2];
    const float* mk = (const float*)d_in[3];
    const float* mv = (const float*)d_in[4];
    const float* mr = (const float*)d_in[5];
    const float* Wk = (const float*)d_in[6];
    const float* Wv = (const float*)d_in[7];
    const float* Wr = (const float*)d_in[8];
    const float* Wo = (const float*)d_in[9];

    const size_t MC = (size_t)Mq * Cq;      // 9,437,184 elems

    // d_out doubles as scratch for xk/xv (2 x bf16 MC = out bytes exactly)
    __bf16* xk = (__bf16*)d_out;
    __bf16* xv = xk + MC;

    // ws: xr | kbuf | vbuf | rbuf(->rwkv) | weights(bf16 x4)  = ~80 MB
    __bf16* xr   = (__bf16*)d_ws;
    __bf16* kbuf = xr + MC;                 // kbuf,vbuf,rbuf contiguous
    __bf16* vbuf = kbuf + MC;
    __bf16* rbuf = vbuf + MC;
    __bf16* Wp   = rbuf + MC;
    __bf16* Wob  = Wp + 3 * 589824;

    prep_kernel<<<11520, 256, 0, stream>>>(x, mk, mv, mr, Wk, Wv, Wr, Wo,
                                           xk, xv, xr, Wp);

    // fused k|v|r GEMM: 18 strips x 96 m-tiles, XCD-swizzled 1-D grid
    mfma_gemm<true><<<18 * 96, 256, 0, stream>>>(
        xk, xv, xr, Wp, kbuf, nullptr);

    scan_kernel<<<dim3(Cq / 128, Bq), dim3(64, SEG), 0, stream>>>(
        kbuf, vbuf, rbuf, td, tf);

    mfma_gemm<false><<<6 * 96, 256, 0, stream>>>(
        rbuf, nullptr, nullptr, Wob, nullptr, (float*)d_out);
}

// Round 8
// 233.576 us; speedup vs baseline: 1.2845x; 1.1666x over previous
//
#include <hip/hip_runtime.h>
#include <math.h>

#define Mq 12288          // B*T
#define Nq 768            // C (per-matrix output width)
#define Kq 768            // C (reduce dim)
#define Tq 768
#define Bq 16
#define Cq 768
#define BK 64             // K-tile (bf16) = 128 B = 8 x 16B chunks
#define BM 64             // M-tile (tokens)

typedef __bf16 bf16x8 __attribute__((ext_vector_type(8)));
typedef __bf16 bf16x4 __attribute__((ext_vector_type(4)));
typedef __bf16 bf16x2 __attribute__((ext_vector_type(2)));
typedef float  floatx4 __attribute__((ext_vector_type(4)));

// async 16B/lane global->LDS (LDS operand is wave-uniform base; HW adds lane*16)
#define GLD_LDS16(g, l) __builtin_amdgcn_global_load_lds(                      \
    (const __attribute__((address_space(1))) unsigned int*)(g),                \
    (__attribute__((address_space(3))) unsigned int*)(l), 16, 0, 0)

// ---------------------------------------------------------------------------
// Fused prep: blocks [0,9216) token-shift mix -> bf16 xk/xv/xr;
//             blocks [9216,11520) weight f32 -> bf16 pool (k|v|r|o rows).
// ---------------------------------------------------------------------------
__global__ __launch_bounds__(256)
void prep_kernel(const float* __restrict__ x,
                 const float* __restrict__ mk, const float* __restrict__ mv,
                 const float* __restrict__ mr,
                 const float* __restrict__ Wk, const float* __restrict__ Wv,
                 const float* __restrict__ Wr, const float* __restrict__ Wo,
                 __bf16* __restrict__ xk, __bf16* __restrict__ xv,
                 __bf16* __restrict__ xr, __bf16* __restrict__ wp)
{
    const int bid = blockIdx.x;
    if (bid < 9216) {
        const int i  = bid * 256 + threadIdx.x;       // one float4 of channels
        const int c4 = i % (Cq / 4);
        const int m  = i / (Cq / 4);
        const int t  = m % Tq;
        const int c0 = c4 * 4;

        const float4 xc = *(const float4*)(x + (size_t)m * Cq + c0);
        float4 xp = make_float4(0.f, 0.f, 0.f, 0.f);
        if (t > 0) xp = *(const float4*)(x + (size_t)(m - 1) * Cq + c0);

        const float4 k4 = *(const float4*)(mk + c0);
        const float4 v4 = *(const float4*)(mv + c0);
        const float4 r4 = *(const float4*)(mr + c0);

        bf16x4 ok = { (__bf16)fmaf(k4.x, xc.x - xp.x, xp.x),
                      (__bf16)fmaf(k4.y, xc.y - xp.y, xp.y),
                      (__bf16)fmaf(k4.z, xc.z - xp.z, xp.z),
                      (__bf16)fmaf(k4.w, xc.w - xp.w, xp.w) };
        bf16x4 ov = { (__bf16)fmaf(v4.x, xc.x - xp.x, xp.x),
                      (__bf16)fmaf(v4.y, xc.y - xp.y, xp.y),
                      (__bf16)fmaf(v4.z, xc.z - xp.z, xp.z),
                      (__bf16)fmaf(v4.w, xc.w - xp.w, xp.w) };
        bf16x4 orr = { (__bf16)fmaf(r4.x, xc.x - xp.x, xp.x),
                       (__bf16)fmaf(r4.y, xc.y - xp.y, xp.y),
                       (__bf16)fmaf(r4.z, xc.z - xp.z, xp.z),
                       (__bf16)fmaf(r4.w, xc.w - xp.w, xp.w) };
        const size_t o = (size_t)m * Cq + c0;
        *(bf16x4*)(xk + o) = ok;
        *(bf16x4*)(xv + o) = ov;
        *(bf16x4*)(xr + o) = orr;
    } else {
        const int i   = (bid - 9216) * 256 + threadIdx.x; // one float4
        const int a   = i / 147456;                       // which matrix
        const int off = (i - a * 147456) * 4;
        const float* s = (a == 0) ? Wk : (a == 1) ? Wv : (a == 2) ? Wr : Wo;
        const float4 v = *(const float4*)(s + off);
        bf16x4 r = { (__bf16)v.x, (__bf16)v.y, (__bf16)v.z, (__bf16)v.w };
        *(bf16x4*)(wp + (size_t)a * 589824 + off) = r;
    }
}

// ---------------------------------------------------------------------------
// bf16 MFMA GEMM (R5-proven config): 64x128 tile, BK=64, 256 thr,
// operand-swapped (W = MFMA A operand -> register dim = 4 consecutive
// channels -> vectorized stores). XOR-8 source-side chunk swizzle (zero
// conflicts measured). 1-D grid, XCD-aware: xcd=blk&7 owns m-tiles
// [xcd*24, xcd*24+24), strip-fastest within -> per-XCD L2 working set =
// all B strips + current A tiles < 4 MB.
// ---------------------------------------------------------------------------
template<bool KVR>
__global__ __launch_bounds__(256, 6)
void mfma_gemm(const __bf16* __restrict__ A0, const __bf16* __restrict__ A1,
               const __bf16* __restrict__ A2,
               const __bf16* __restrict__ W,
               __bf16* __restrict__ OUTb, float* __restrict__ OUTf)
{
    __shared__ __bf16 As[BM * BK];    //  8 KB (tokens)
    __shared__ __bf16 Bs[128 * BK];   // 16 KB (channels)

    const int STRIPS = KVR ? 18 : 6;

    // ---- XCD-aware block swizzle (8 XCDs, 192 m-tiles = 8 x 24)
    const int i_    = blockIdx.x;
    const int xcd   = i_ & 7;
    const int j_    = i_ >> 3;
    const int strip = j_ % STRIPS;
    const int mt    = xcd * 24 + j_ / STRIPS;

    const int tid   = threadIdx.x;
    const int wave  = tid >> 6;
    const int lane  = tid & 63;
    const int m0    = mt * BM;
    const int matid = KVR ? strip / 6 : 0;
    const int n0    = KVR ? (strip % 6) * 128 : strip * 128;
    const int wn0   = strip * 128;

    const __bf16* A = KVR ? (matid == 0 ? A0 : matid == 1 ? A1 : A2) : A0;

    // ---- staging: 1024 B per global_load_lds instr = 8 rows of 128 B
    const int r8 = lane >> 3;             // row within 8-row group
    const int sc = (lane & 7) ^ r8;       // XOR-8 swizzled source chunk
    const __bf16* gA[2];  __bf16* lA[2];
    const __bf16* gB[4];  __bf16* lB[4];
#pragma unroll
    for (int i = 0; i < 2; ++i) {
        const int row = (wave * 2 + i) * 8 + r8;
        gA[i] = A + (size_t)(m0 + row) * Kq + sc * 8;
        lA[i] = As + (wave * 2 + i) * 512;
    }
#pragma unroll
    for (int i = 0; i < 4; ++i) {
        const int row = (wave * 4 + i) * 8 + r8;
        gB[i] = W + (size_t)(wn0 + row) * Kq + sc * 8;
        lB[i] = Bs + (wave * 4 + i) * 512;
    }

    // ---- reader coords
    const int qm = wave & 1;              // token half (32)
    const int qn = wave >> 1;             // channel half (64)
    const int xRow = qm * 32 + (lane & 15);   // + j*16, in As
    const int wRow = qn * 64 + (lane & 15);   // + i*16, in Bs
    const int lk   = lane >> 4;               // logical 16B chunk within K=32

    floatx4 acc[4][2];
#pragma unroll
    for (int i = 0; i < 4; ++i)
#pragma unroll
        for (int j = 0; j < 2; ++j) acc[i][j] = (floatx4){0.f, 0.f, 0.f, 0.f};

    for (int kt = 0; kt < Kq / BK; ++kt) {
#pragma unroll
        for (int i = 0; i < 2; ++i) { GLD_LDS16(gA[i], lA[i]); gA[i] += BK; }
#pragma unroll
        for (int i = 0; i < 4; ++i) { GLD_LDS16(gB[i], lB[i]); gB[i] += BK; }
        __syncthreads();                  // drains vmcnt(0): tile in LDS

#pragma unroll
        for (int kk = 0; kk < 2; ++kk) {
            bf16x8 wF[4], xF[2];
#pragma unroll
            for (int i = 0; i < 4; ++i) {
                const int r = wRow + i * 16;
                wF[i] = *(const bf16x8*)(Bs + r * BK +
                                         (((kk << 2) | lk) ^ (r & 7)) * 8);
            }
#pragma unroll
            for (int j = 0; j < 2; ++j) {
                const int r = xRow + j * 16;
                xF[j] = *(const bf16x8*)(As + r * BK +
                                         (((kk << 2) | lk) ^ (r & 7)) * 8);
            }
#pragma unroll
            for (int i = 0; i < 4; ++i)
#pragma unroll
                for (int j = 0; j < 2; ++j)
                    acc[i][j] = __builtin_amdgcn_mfma_f32_16x16x32_bf16(
                        wF[i], xF[j], acc[i][j], 0, 0, 0);
        }
        __syncthreads();                  // LDS reads done before overwrite
    }

    // ---- epilogue: D col = token (lane&15), row-reg = 4 consecutive channels
#pragma unroll
    for (int j = 0; j < 2; ++j) {
        const int tok = m0 + qm * 32 + j * 16 + (lane & 15);
#pragma unroll
        for (int i = 0; i < 4; ++i) {
            const int ch = n0 + qn * 64 + i * 16 + (lane >> 4) * 4;
            if (KVR) {
                float v0 = acc[i][j][0], v1 = acc[i][j][1];
                float v2 = acc[i][j][2], v3 = acc[i][j][3];
                if (matid == 0) {
                    v0 = expf(fminf(v0, 60.f)); v1 = expf(fminf(v1, 60.f));
                    v2 = expf(fminf(v2, 60.f)); v3 = expf(fminf(v3, 60.f));
                } else if (matid == 2) {
                    v0 = 1.f / (1.f + expf(-v0)); v1 = 1.f / (1.f + expf(-v1));
                    v2 = 1.f / (1.f + expf(-v2)); v3 = 1.f / (1.f + expf(-v3));
                }
                bf16x4 o = { (__bf16)v0, (__bf16)v1, (__bf16)v2, (__bf16)v3 };
                *(bf16x4*)(OUTb + (size_t)matid * Mq * Nq +
                           (size_t)tok * Nq + ch) = o;
            } else {
                floatx4 o = acc[i][j];
                *(floatx4*)(OUTf + (size_t)tok * Nq + ch) = o;
            }
        }
    }
}

// ---------------------------------------------------------------------------
// Segmented RWKV scan, re-gridded for CU coverage: block = (16 ch-pairs x
// 16 segments) = 256 thr covering 32 channels of one batch; grid (24,16) =
// 384 blocks (vs 96 before -> 4x CU coverage). Segments of 48 steps; LDS
// prefix combine; rwkv (bf16) overwrites rbuf in place.
// ---------------------------------------------------------------------------
#define SEG 16
#define SLEN (Tq / SEG)   // 48
#define SCH 32            // channels per block

__global__ __launch_bounds__(256)
void scan_kernel(const __bf16* __restrict__ kb, const __bf16* __restrict__ vb,
                 __bf16* rb,
                 const float* __restrict__ td, const float* __restrict__ tf)
{
    __shared__ float2 aS[SEG][SCH / 2];
    __shared__ float2 bS[SEG][SCH / 2];

    const int cx  = threadIdx.x;          // 0..15 -> channel pair
    const int seg = threadIdx.y;          // 0..15
    const int c0  = blockIdx.x * SCH + cx * 2;
    const int b   = blockIdx.y;

    const float d0 = expf(td[c0]),     d1 = expf(td[c0 + 1]);
    const float w0 = expf(-d0),        w1 = expf(-d1);      // per-step decay
    const float u0 = expf(tf[c0]),     u1 = expf(tf[c0 + 1]);

    const size_t base = ((size_t)b * Tq + seg * SLEN) * Cq + c0;

    // phase 1: local segment sums (zero init)
    float a0 = 0.f, a1 = 0.f, s0 = 0.f, s1 = 0.f;
#pragma unroll 4
    for (int t = 0; t < SLEN; ++t) {
        const size_t idx = base + (size_t)t * Cq;
        const bf16x2 k2 = *(const bf16x2*)(kb + idx);
        const bf16x2 v2 = *(const bf16x2*)(vb + idx);
        const float k0 = (float)k2[0], k1 = (float)k2[1];
        a0 = fmaf(w0, a0, k0 * (float)v2[0]);
        a1 = fmaf(w1, a1, k1 * (float)v2[1]);
        s0 = fmaf(w0, s0, k0);
        s1 = fmaf(w1, s1, k1);
    }
    aS[seg][cx] = make_float2(a0, a1);
    bS[seg][cx] = make_float2(s0, s1);
    __syncthreads();

    // phase 2: serial prefix over segments (threads with seg==0)
    if (seg == 0) {
        const float W0 = expf(-d0 * (float)SLEN);   // w0^SLEN
        const float W1 = expf(-d1 * (float)SLEN);
        float ia0 = 0.f, ia1 = 0.f, ib0 = 0.f, ib1 = 0.f;
#pragma unroll
        for (int s = 0; s < SEG; ++s) {
            const float2 ta = aS[s][cx];
            const float2 tb = bS[s][cx];
            aS[s][cx] = make_float2(ia0, ia1);
            bS[s][cx] = make_float2(ib0, ib1);
            ia0 = fmaf(W0, ia0, ta.x);  ia1 = fmaf(W1, ia1, ta.y);
            ib0 = fmaf(W0, ib0, tb.x);  ib1 = fmaf(W1, ib1, tb.y);
        }
    }
    __syncthreads();

    // phase 3: outputs with incoming state
    const float2 ain = aS[seg][cx];
    const float2 bin = bS[seg][cx];
    a0 = ain.x; a1 = ain.y; s0 = bin.x; s1 = bin.y;
#pragma unroll 2
    for (int t = 0; t < SLEN; ++t) {
        const size_t idx = base + (size_t)t * Cq;
        const bf16x2 k2 = *(const bf16x2*)(kb + idx);
        const bf16x2 v2 = *(const bf16x2*)(vb + idx);
        const bf16x2 r2 = *(const bf16x2*)(rb + idx);   // sigmoid(r)
        const float k0 = (float)k2[0], k1 = (float)k2[1];
        const float kv0 = k0 * (float)v2[0], kv1 = k1 * (float)v2[1];
        const float n0 = fmaf(u0, kv0, a0), n1 = fmaf(u1, kv1, a1);
        const float e0 = fmaf(u0, k0, s0) + 1e-8f;
        const float e1 = fmaf(u1, k1, s1) + 1e-8f;
        bf16x2 o = { (__bf16)((float)r2[0] * n0 / e0),
                     (__bf16)((float)r2[1] * n1 / e1) };
        *(bf16x2*)(rb + idx) = o;
        a0 = fmaf(w0, a0, kv0);  a1 = fmaf(w1, a1, kv1);
        s0 = fmaf(w0, s0, k0);   s1 = fmaf(w1, s1, k1);
    }
}

extern "C" void kernel_launch(void* const* d_in, const int* in_sizes, int n_in,
                              void* d_out, int out_size, void* d_ws, size_t ws_size,
                              hipStream_t stream)
{
    const float* x  = (const float*)d_in[0];
    const float* td = (const float*)d_in[1];
    const float* tf = (const float*)d_in[2];
    const float* mk = (const float*)d_in[3];
    const float* mv = (const float*)d_in[4];
    const float* mr = (const float*)d_in[5];
    const float* Wk = (const float*)d_in[6];
    const float* Wv = (const float*)d_in[7];
    const float* Wr = (const float*)d_in[8];
    const float* Wo = (const float*)d_in[9];

    const size_t MC = (size_t)Mq * Cq;      // 9,437,184 elems

    // d_out doubles as scratch for xk/xv (2 x bf16 MC = out bytes exactly)
    __bf16* xk = (__bf16*)d_out;
    __bf16* xv = xk + MC;

    // ws: xr | kbuf | vbuf | rbuf(->rwkv) | weights(bf16 x4)  = ~80 MB
    __bf16* xr   = (__bf16*)d_ws;
    __bf16* kbuf = xr + MC;                 // kbuf,vbuf,rbuf contiguous
    __bf16* vbuf = kbuf + MC;
    __bf16* rbuf = vbuf + MC;
    __bf16* Wp   = rbuf + MC;
    __bf16* Wob  = Wp + 3 * 589824;

    prep_kernel<<<11520, 256, 0, stream>>>(x, mk, mv, mr, Wk, Wv, Wr, Wo,
                                           xk, xv, xr, Wp);

    // fused k|v|r GEMM: 18 strips x 192 m-tiles, XCD-swizzled 1-D grid
    mfma_gemm<true><<<18 * 192, 256, 0, stream>>>(
        xk, xv, xr, Wp, kbuf, nullptr);

    scan_kernel<<<dim3(Cq / SCH, Bq), dim3(16, SEG), 0, stream>>>(
        kbuf, vbuf, rbuf, td, tf);

    mfma_gemm<false><<<6 * 192, 256, 0, stream>>>(
        rbuf, nullptr, nullptr, Wob, nullptr, (float*)d_out);
}